// Round 3
// baseline (94.451 us; speedup 1.0000x reference)
//
#include <hip/hip_runtime.h>

#define BB 64
#define TT 256
#define HH 200
#define KK 48
#define C4 50        // HH/4 float4 per row
#define TPB 16       // t rows per block tile
#define FS4 51       // LDS row stride in float4 (odd -> conflict-free b128)

__global__ __launch_bounds__(256, 2)
void crf_fused_kernel(const float* __restrict__ feats,
                      const float* __restrict__ W_e,
                      const float* __restrict__ b_e,
                      const int*   __restrict__ targets,
                      const int*   __restrict__ mask,
                      const int*   __restrict__ end_tag_p,
                      float*       __restrict__ out)
{
    __shared__ float4 f_lds[TPB * FS4];                 // 13056 B
    __shared__ float  m_arr[4][TPB], s_arr[4][TPB];
    __shared__ float  g_arr[4][TPB], e_arr[4][TPB];

    const int tid  = threadIdx.x;
    const int lane = tid & 63;
    const int w    = tid >> 6;          // wave id 0..3 -> k-dozen
    const int bidx = blockIdx.x >> 4;   // batch
    const int tq   = blockIdx.x & 15;   // t-tile of 16

    // ---- stage feats tile (16 rows x 50 float4), coalesced ----
    const float4* feats4 = reinterpret_cast<const float4*>(feats) +
                           (size_t)(bidx * TT + tq * TPB) * C4;
    for (int i = tid; i < TPB * C4; i += 256) {
        const int r = i / C4, c = i - r * C4;
        f_lds[r * FS4 + c] = feats4[i];
    }

    // ---- wave-redundant mask length (one int4 per lane covers all 256 t) ----
    int len;
    {
        const int4 mv4 = reinterpret_cast<const int4*>(mask + bidx * TT)[lane];
        int mv = mv4.x + mv4.y + mv4.z + mv4.w;
        #pragma unroll
        for (int off = 32; off >= 1; off >>= 1) mv += __shfl_xor(mv, off);
        len = mv;
    }
    __syncthreads();

    // ---- lane mapping: t_loc = lane&15, k-group = lane>>4; 3 k's per lane ----
    const int t_loc  = lane & 15;
    const int kg     = lane >> 4;            // 0..3
    const int k0     = w * 12 + kg * 3;      // lane owns k0..k0+2
    const int t_glob = tq * TPB + t_loc;

    const float4* W4   = reinterpret_cast<const float4*>(W_e);
    const float4* wp0  = W4 + (size_t)(k0 + 0) * C4;
    const float4* wp1  = W4 + (size_t)(k0 + 1) * C4;
    const float4* wp2  = W4 + (size_t)(k0 + 2) * C4;
    const float4* frow = &f_lds[t_loc * FS4];

    float a0 = b_e[k0], a1 = b_e[k0 + 1], a2 = b_e[k0 + 2];

    // ---- distance-2 software pipeline: 8 loads in flight, static indexing ----
    float4 fB[2], w0B[2], w1B[2], w2B[2];
    fB[0] = frow[0]; w0B[0] = wp0[0]; w1B[0] = wp1[0]; w2B[0] = wp2[0];
    fB[1] = frow[1]; w0B[1] = wp0[1]; w1B[1] = wp1[1]; w2B[1] = wp2[1];

    #pragma unroll
    for (int c = 0; c < C4; ++c) {
        const int cur = c & 1;               // static after full unroll
        const float4 f  = fB[cur];
        const float4 w0 = w0B[cur];
        const float4 w1 = w1B[cur];
        const float4 w2 = w2B[cur];
        const int cn = c + 2;
        if (cn < C4) {                       // prefetch c+2 into freed slot
            fB[cur]  = frow[cn];
            w0B[cur] = wp0[cn];
            w1B[cur] = wp1[cn];
            w2B[cur] = wp2[cn];
        }
        a0 = fmaf(f.x,w0.x, fmaf(f.y,w0.y, fmaf(f.z,w0.z, fmaf(f.w,w0.w, a0))));
        a1 = fmaf(f.x,w1.x, fmaf(f.y,w1.y, fmaf(f.z,w1.z, fmaf(f.w,w1.w, a1))));
        a2 = fmaf(f.x,w2.x, fmaf(f.y,w2.y, fmaf(f.z,w2.z, fmaf(f.w,w2.w, a2))));
    }

    // ---- per-lane partials over its 3 k's ----
    const int ET  = end_tag_p[0];
    const int tgt = targets[bidx * TT + t_glob] % KK;

    float m = fmaxf(fmaxf(a0, a1), a2);
    float s = expf(a0 - m) + expf(a1 - m) + expf(a2 - m);
    float g = ((k0     == tgt) ? a0 : 0.0f)
            + ((k0 + 1 == tgt) ? a1 : 0.0f)
            + ((k0 + 2 == tgt) ? a2 : 0.0f);
    float e = ((k0     == ET) ? a0 : 0.0f)
            + ((k0 + 1 == ET) ? a1 : 0.0f)
            + ((k0 + 2 == ET) ? a2 : 0.0f);

    // ---- merge the 4 k-groups in-register (lanes xor 16, 32) ----
    #pragma unroll
    for (int off = 16; off <= 32; off <<= 1) {
        const float om = __shfl_xor(m, off);
        const float os = __shfl_xor(s, off);
        const float nm = fmaxf(m, om);
        s = s * expf(m - nm) + os * expf(om - nm);
        m = nm;
        g += __shfl_xor(g, off);
        e += __shfl_xor(e, off);
    }
    if (lane < TPB) {
        m_arr[w][t_loc] = m; s_arr[w][t_loc] = s;
        g_arr[w][t_loc] = g; e_arr[w][t_loc] = e;
    }
    __syncthreads();

    // ---- final: combine 4 waves per t, form contribution, reduce 16 t ----
    if (tid < TPB) {
        const int t = tid;
        float M = m_arr[0][t], S = s_arr[0][t];
        #pragma unroll
        for (int i2 = 1; i2 < 4; ++i2) {
            const float om = m_arr[i2][t], os = s_arr[i2][t];
            const float nm = fmaxf(M, om);
            S = S * expf(M - nm) + os * expf(om - nm);
            M = nm;
        }
        const float lse  = M + logf(S);
        const float gold = g_arr[0][t] + g_arr[1][t] + g_arr[2][t] + g_arr[3][t];
        const float eend = e_arr[0][t] + e_arr[1][t] + e_arr[2][t] + e_arr[3][t];
        const int gt = tq * TPB + t;

        float c = 0.0f;
        if (gt < len)          c -= gold;
        if (gt == len - 1)     c += eend;
        else if (gt < len - 1) c += lse;

        #pragma unroll
        for (int off = 8; off >= 1; off >>= 1) c += __shfl_xor(c, off);
        if (t == 0) atomicAdd(out + bidx, c);
    }
}

extern "C" void kernel_launch(void* const* d_in, const int* in_sizes, int n_in,
                              void* d_out, int out_size, void* d_ws, size_t ws_size,
                              hipStream_t stream) {
    const float* feats   = (const float*)d_in[0];
    const float* W_e     = (const float*)d_in[1];
    const float* b_e     = (const float*)d_in[2];
    const int*   targets = (const int*)d_in[3];
    const int*   mask    = (const int*)d_in[4];
    const int*   et      = (const int*)d_in[6];
    float*       out     = (float*)d_out;

    hipMemsetAsync(out, 0, BB * sizeof(float), stream);
    crf_fused_kernel<<<dim3(BB * (TT / TPB)), dim3(256), 0, stream>>>(
        feats, W_e, b_e, targets, mask, et, out);
}

// Round 4
// 79.157 us; speedup vs baseline: 1.1932x; 1.1932x over previous
//
#include <hip/hip_runtime.h>
#include <hip/hip_bf16.h>

#define BB 64
#define TT 256
#define HH 200
#define KK 48
#define C4 50          // HH/4 float4 per row
#define AS 216         // LDS row stride in bf16 elems (432B: 16B-aligned, ~2-way banks)

typedef __attribute__((ext_vector_type(8))) short bf16x8;
typedef __attribute__((ext_vector_type(4))) float f32x4;

static __device__ __forceinline__ unsigned short f2bf(float x) {
    __hip_bfloat16 h = __float2bfloat16(x);   // RNE, single v_cvt
    return *reinterpret_cast<unsigned short*>(&h);
}

__global__ __launch_bounds__(256)
void crf_mfma_kernel(const float* __restrict__ feats,
                     const float* __restrict__ W_e,
                     const float* __restrict__ b_e,
                     const int*   __restrict__ targets,
                     const int*   __restrict__ mask,
                     const int*   __restrict__ end_tag_p,
                     float*       __restrict__ out)
{
    __shared__ __align__(16) unsigned short Albs[64 * AS];  // 27648 B feats tile (bf16)
    __shared__ __align__(16) unsigned short Wlds[48 * AS];  // 20736 B W (bf16)
    __shared__ float wpart[4];

    const int tid  = threadIdx.x;
    const int lane = tid & 63;
    const int w    = tid >> 6;          // wave 0..3 -> 16-row M stripe
    const int bidx = blockIdx.x >> 2;   // batch
    const int tq   = blockIdx.x & 3;    // 64-t tile

    // ---- stage feats tile (64 x 200 f32 -> bf16), coalesced ----
    {
        const float4* f4 = reinterpret_cast<const float4*>(feats) +
                           (size_t)(bidx * TT + tq * 64) * C4;
        for (int i = tid; i < 64 * C4; i += 256) {
            const int r = i / C4, cc = i - r * C4;
            const float4 v = f4[i];
            ushort4 o = { f2bf(v.x), f2bf(v.y), f2bf(v.z), f2bf(v.w) };
            *reinterpret_cast<ushort4*>(&Albs[r * AS + cc * 4]) = o;
        }
        const float4* w4 = reinterpret_cast<const float4*>(W_e);
        for (int i = tid; i < KK * C4; i += 256) {
            const int r = i / C4, cc = i - r * C4;
            const float4 v = w4[i];
            ushort4 o = { f2bf(v.x), f2bf(v.y), f2bf(v.z), f2bf(v.w) };
            *reinterpret_cast<ushort4*>(&Wlds[r * AS + cc * 4]) = o;
        }
    }

    // ---- wave-redundant mask length ----
    int len;
    {
        const int4 mv4 = reinterpret_cast<const int4*>(mask + bidx * TT)[lane];
        int mv = mv4.x + mv4.y + mv4.z + mv4.w;
        #pragma unroll
        for (int off = 32; off >= 1; off >>= 1) mv += __shfl_xor(mv, off);
        len = mv;
    }
    __syncthreads();

    // ---- MFMA: wave w computes rows [w*16, w*16+16) x 48 k ----
    const int rg = lane >> 4;   // k-group 0..3 (k = kc*32 + rg*8 + j)
    const int cc = lane & 15;   // A-row-within-stripe / B-col / D-col

    const unsigned short* Ap  = &Albs[(w * 16 + cc) * AS];
    const unsigned short* Bp0 = &Wlds[(0  + cc) * AS];
    const unsigned short* Bp1 = &Wlds[(16 + cc) * AS];
    const unsigned short* Bp2 = &Wlds[(32 + cc) * AS];

    f32x4 ac0 = {0.f, 0.f, 0.f, 0.f};
    f32x4 ac1 = {0.f, 0.f, 0.f, 0.f};
    f32x4 ac2 = {0.f, 0.f, 0.f, 0.f};

    #pragma unroll
    for (int kc = 0; kc < 7; ++kc) {
        const int koff = kc * 32 + rg * 8;
        bf16x8 a, b0, b1, b2;
        if (kc < 6 || rg == 0) {          // chunk 6: only k-group 0 covers k<200
            a  = *reinterpret_cast<const bf16x8*>(Ap  + koff);
            b0 = *reinterpret_cast<const bf16x8*>(Bp0 + koff);
            b1 = *reinterpret_cast<const bf16x8*>(Bp1 + koff);
            b2 = *reinterpret_cast<const bf16x8*>(Bp2 + koff);
        } else {
            a = (bf16x8)(short)0; b0 = a; b1 = a; b2 = a;
        }
        ac0 = __builtin_amdgcn_mfma_f32_16x16x32_bf16(a, b0, ac0, 0, 0, 0);
        ac1 = __builtin_amdgcn_mfma_f32_16x16x32_bf16(a, b1, ac1, 0, 0, 0);
        ac2 = __builtin_amdgcn_mfma_f32_16x16x32_bf16(a, b2, ac2, 0, 0, 0);
    }

    // ---- epilogue: lane holds em[row = w*16 + rg*4 + j][k = {0,16,32}+cc] ----
    const float bb0 = b_e[cc], bb1 = b_e[16 + cc], bb2 = b_e[32 + cc];
    const int   ET  = end_tag_p[0];

    float csum = 0.0f;
    #pragma unroll
    for (int j = 0; j < 4; ++j) {
        const float x0 = ac0[j] + bb0;
        const float x1 = ac1[j] + bb1;
        const float x2 = ac2[j] + bb2;

        const int r  = w * 16 + rg * 4 + j;    // row within 64-t tile
        const int gt = tq * 64 + r;            // global t
        const int tg = targets[bidx * TT + gt] % KK;

        // max over the row (3 local + butterfly over 16 lanes)
        float mx = fmaxf(fmaxf(x0, x1), x2);
        #pragma unroll
        for (int off = 8; off >= 1; off >>= 1) mx = fmaxf(mx, __shfl_xor(mx, off));
        // sumexp
        float s = expf(x0 - mx) + expf(x1 - mx) + expf(x2 - mx);
        // gold / end picks
        float g = ((0  + cc) == tg ? x0 : 0.f) + ((16 + cc) == tg ? x1 : 0.f)
                + ((32 + cc) == tg ? x2 : 0.f);
        float e = ((0  + cc) == ET ? x0 : 0.f) + ((16 + cc) == ET ? x1 : 0.f)
                + ((32 + cc) == ET ? x2 : 0.f);
        #pragma unroll
        for (int off = 8; off >= 1; off >>= 1) {
            s += __shfl_xor(s, off);
            g += __shfl_xor(g, off);
            e += __shfl_xor(e, off);
        }
        const float lse = mx + logf(s);

        float cr = 0.0f;
        if (gt < len)          cr -= g;
        if (gt == len - 1)     cr += e;
        else if (gt < len - 1) cr += lse;
        csum += cr;
    }

    // ---- one contribution per row: keep lanes cc==0, fold wave, fold block ----
    float v = (cc == 0) ? csum : 0.0f;
    v += __shfl_xor(v, 16);
    v += __shfl_xor(v, 32);
    if (lane == 0) wpart[w] = v;
    __syncthreads();
    if (tid == 0) {
        atomicAdd(out + bidx, wpart[0] + wpart[1] + wpart[2] + wpart[3]);
    }
}

extern "C" void kernel_launch(void* const* d_in, const int* in_sizes, int n_in,
                              void* d_out, int out_size, void* d_ws, size_t ws_size,
                              hipStream_t stream) {
    const float* feats   = (const float*)d_in[0];
    const float* W_e     = (const float*)d_in[1];
    const float* b_e     = (const float*)d_in[2];
    const int*   targets = (const int*)d_in[3];
    const int*   mask    = (const int*)d_in[4];
    const int*   et      = (const int*)d_in[6];
    float*       out     = (float*)d_out;

    hipMemsetAsync(out, 0, BB * sizeof(float), stream);
    crf_mfma_kernel<<<dim3(BB * 4), dim3(256), 0, stream>>>(
        feats, W_e, b_e, targets, mask, et, out);
}